// Round 2
// baseline (26.233 us; speedup 1.0000x reference)
//
#include <hip/hip_runtime.h>
#include <hip/hip_bf16.h>
#include <math.h>

// scores[s] = sum_d E[s,d] * h[d]; out[s] = sigmoid(scores[s])
// One 64-lane wave per 4 consecutive rows. hidden (4 KiB) hoisted into
// registers once per wave (4x float4/lane) and reused across the 4 rows.
// d = 1024 floats = 256 float4; lane i covers vec indices i, i+64, i+128, i+192.

__device__ __forceinline__ float dot4(float4 a, float4 b) {
    return a.x * b.x + a.y * b.y + a.z * b.z + a.w * b.w;
}

__global__ __launch_bounds__(256) void attn_matvec_sigmoid4(
        const float* __restrict__ h,
        const float* __restrict__ E,
        float* __restrict__ out,
        int seq_len, int d) {
    const int waves_per_block = blockDim.x >> 6;
    const int wave = blockIdx.x * waves_per_block + (threadIdx.x >> 6);
    const int lane = threadIdx.x & 63;
    const int total_waves = gridDim.x * waves_per_block;

    const float4* __restrict__ hv = reinterpret_cast<const float4*>(h);
    // hidden in registers, reused for every row this wave touches
    const float4 h0 = hv[lane];
    const float4 h1 = hv[lane + 64];
    const float4 h2 = hv[lane + 128];
    const float4 h3 = hv[lane + 192];

    const int nvec_row = d >> 2;  // 256 float4 per row

    for (int base = wave * 4; base < seq_len; base += total_waves * 4) {
        float acc0 = 0.f, acc1 = 0.f, acc2 = 0.f, acc3 = 0.f;

        const float4* r0 = reinterpret_cast<const float4*>(E + (size_t)(base + 0) * d);
        const float4* r1 = reinterpret_cast<const float4*>(E + (size_t)(base + 1) * d);
        const float4* r2 = reinterpret_cast<const float4*>(E + (size_t)(base + 2) * d);
        const float4* r3 = reinterpret_cast<const float4*>(E + (size_t)(base + 3) * d);

        // 16 independent 16B loads in flight
        float4 a0 = r0[lane],       b0 = r1[lane],       c0 = r2[lane],       e0 = r3[lane];
        float4 a1 = r0[lane + 64],  b1 = r1[lane + 64],  c1 = r2[lane + 64],  e1 = r3[lane + 64];
        float4 a2 = r0[lane + 128], b2 = r1[lane + 128], c2 = r2[lane + 128], e2 = r3[lane + 128];
        float4 a3 = r0[lane + 192], b3 = r1[lane + 192], c3 = r2[lane + 192], e3 = r3[lane + 192];

        acc0 = dot4(a0, h0) + dot4(a1, h1) + dot4(a2, h2) + dot4(a3, h3);
        acc1 = dot4(b0, h0) + dot4(b1, h1) + dot4(b2, h2) + dot4(b3, h3);
        acc2 = dot4(c0, h0) + dot4(c1, h1) + dot4(c2, h2) + dot4(c3, h3);
        acc3 = dot4(e0, h0) + dot4(e1, h1) + dot4(e2, h2) + dot4(e3, h3);

        // 64-lane butterfly reductions
#pragma unroll
        for (int off = 32; off > 0; off >>= 1) {
            acc0 += __shfl_xor(acc0, off, 64);
            acc1 += __shfl_xor(acc1, off, 64);
            acc2 += __shfl_xor(acc2, off, 64);
            acc3 += __shfl_xor(acc3, off, 64);
        }

        if (lane == 0) {
            float4 o;
            o.x = 1.0f / (1.0f + __expf(-acc0));
            o.y = 1.0f / (1.0f + __expf(-acc1));
            o.z = 1.0f / (1.0f + __expf(-acc2));
            o.w = 1.0f / (1.0f + __expf(-acc3));
            *reinterpret_cast<float4*>(out + base) = o;
        }
    }
}

extern "C" void kernel_launch(void* const* d_in, const int* in_sizes, int n_in,
                              void* d_out, int out_size, void* d_ws, size_t ws_size,
                              hipStream_t stream) {
    const float* hidden = (const float*)d_in[0];   // [1024]
    const float* enc    = (const float*)d_in[1];   // [32768, 1024]
    float* out          = (float*)d_out;           // flat 32768

    const int d = in_sizes[0];        // 1024
    const int seq_len = out_size;     // 32768 (multiple of 4)

    const int block = 256;                       // 4 waves/block
    const int waves_per_block = block / 64;
    const int rows_per_wave = 4;
    int waves_needed = (seq_len + rows_per_wave - 1) / rows_per_wave;   // 8192
    int grid = (waves_needed + waves_per_block - 1) / waves_per_block;  // 2048

    attn_matvec_sigmoid4<<<grid, block, 0, stream>>>(hidden, enc, out, seq_len, d);
}

// Round 3
// 24.977 us; speedup vs baseline: 1.0503x; 1.0503x over previous
//
#include <hip/hip_runtime.h>
#include <hip/hip_bf16.h>
#include <math.h>

// scores[s] = sum_d E[s,d] * h[d]; out[s] = sigmoid(scores[s])
// Persistent: 2048 blocks x 4 waves = 8192 waves (exactly 8 waves/SIMD
// resident at full occupancy); each wave grid-strides over 4 rows.
// hidden (4 KiB) hoisted into 16 VGPRs once per wave, reused for all rows.

__device__ __forceinline__ float dot4(float4 a, float4 b) {
    return a.x * b.x + a.y * b.y + a.z * b.z + a.w * b.w;
}

__global__ __launch_bounds__(256, 8) void attn_matvec_sigmoid_p(
        const float* __restrict__ h,
        const float* __restrict__ E,
        float* __restrict__ out,
        int seq_len, int d) {
    const int lane = threadIdx.x & 63;
    const int wave = blockIdx.x * (blockDim.x >> 6) + (threadIdx.x >> 6);
    const int total_waves = gridDim.x * (blockDim.x >> 6);

    const float4* __restrict__ hv = reinterpret_cast<const float4*>(h);
    // hidden in registers for the whole persistent wave
    const float4 h0 = hv[lane];
    const float4 h1 = hv[lane + 64];
    const float4 h2 = hv[lane + 128];
    const float4 h3 = hv[lane + 192];

    for (int row = wave; row < seq_len; row += total_waves) {
        const float4* __restrict__ r =
            reinterpret_cast<const float4*>(E + (size_t)row * d);
        // 4 independent 16B loads in flight; only one row's data live -> low VGPR
        float4 a0 = r[lane];
        float4 a1 = r[lane + 64];
        float4 a2 = r[lane + 128];
        float4 a3 = r[lane + 192];

        float acc = dot4(a0, h0) + dot4(a1, h1) + dot4(a2, h2) + dot4(a3, h3);

#pragma unroll
        for (int off = 32; off > 0; off >>= 1)
            acc += __shfl_xor(acc, off, 64);

        if (lane == 0)
            out[row] = 1.0f / (1.0f + __expf(-acc));
    }
}

extern "C" void kernel_launch(void* const* d_in, const int* in_sizes, int n_in,
                              void* d_out, int out_size, void* d_ws, size_t ws_size,
                              hipStream_t stream) {
    const float* hidden = (const float*)d_in[0];   // [1024]
    const float* enc    = (const float*)d_in[1];   // [32768, 1024]
    float* out          = (float*)d_out;           // flat 32768

    const int d = in_sizes[0];        // 1024
    const int seq_len = out_size;     // 32768

    const int block = 256;            // 4 waves/block
    const int grid = 2048;            // 8 blocks/CU -> 8192 resident waves

    attn_matvec_sigmoid_p<<<grid, block, 0, stream>>>(hidden, enc, out, seq_len, d);
}